// Round 7
// baseline (232.912 us; speedup 1.0000x reference)
//
#include <hip/hip_runtime.h>
#include <hip/hip_fp16.h>
#include <cmath>

// GraphSAGE forward for MI355X (gfx950).
// R7: occupancy fix for row-parallel kernels (16 rows / 256-thr block -> 3125
//     blocks, was 1563 with 8-row serial chains at 29% occupancy), and
//     2-edges-per-load gather (half2 split-wave: lanes 0-31 even edges,
//     32-63 odd edges; 16 edges in flight at 8-unroll).

#define SCAN_BS 512
#define NXCD 8

// --- Partitioned degree count ---
__global__ __launch_bounds__(256) void count_deg_part(const int* __restrict__ src,
                                                      int* __restrict__ deg, int E, int N) {
    int g    = blockIdx.x & (NXCD - 1);
    int bpg  = blockIdx.x >> 3;
    int nbpg = gridDim.x >> 3;
    int chunk = (N + NXCD - 1) / NXCD;
    int lo = g * chunk;
    int hi = min(N, lo + chunk);
    for (int e = bpg * 256 + threadIdx.x; e < E; e += nbpg * 256) {
        int s = src[e];
        if (s >= lo && s < hi) atomicAdd(&deg[s], 1);
    }
}

// --- 3-phase exclusive scan of deg[N] -> rowptr[N+1] (+ cursor copy) ---
__global__ __launch_bounds__(SCAN_BS) void scan1_kernel(const int* __restrict__ deg,
                                                        int* __restrict__ chunkScan,
                                                        int* __restrict__ blockSums, int N) {
    __shared__ int tmp[SCAN_BS];
    int gid = blockIdx.x * SCAN_BS + threadIdx.x;
    int v = (gid < N) ? deg[gid] : 0;
    tmp[threadIdx.x] = v;
    __syncthreads();
    for (int off = 1; off < SCAN_BS; off <<= 1) {
        int add = (threadIdx.x >= off) ? tmp[threadIdx.x - off] : 0;
        __syncthreads();
        tmp[threadIdx.x] += add;
        __syncthreads();
    }
    if (gid < N) chunkScan[gid] = tmp[threadIdx.x] - v;
    if (threadIdx.x == SCAN_BS - 1) blockSums[blockIdx.x] = tmp[threadIdx.x];
}

__global__ __launch_bounds__(SCAN_BS) void scan2_kernel(int* __restrict__ blockSums, int nb) {
    __shared__ int tmp[SCAN_BS];
    int v = (threadIdx.x < nb) ? blockSums[threadIdx.x] : 0;
    tmp[threadIdx.x] = v;
    __syncthreads();
    for (int off = 1; off < SCAN_BS; off <<= 1) {
        int add = (threadIdx.x >= off) ? tmp[threadIdx.x - off] : 0;
        __syncthreads();
        tmp[threadIdx.x] += add;
        __syncthreads();
    }
    if (threadIdx.x < nb) blockSums[threadIdx.x] = tmp[threadIdx.x] - v;
}

__global__ void scan3_kernel(const int* __restrict__ chunkScan, const int* __restrict__ blockSums,
                             int* __restrict__ rowptr, int* __restrict__ cursor, int N, int E) {
    int gid = blockIdx.x * blockDim.x + threadIdx.x;
    if (gid < N) {
        int v = chunkScan[gid] + blockSums[gid / SCAN_BS];
        rowptr[gid] = v;
        cursor[gid] = v;
    }
    if (gid == 0) rowptr[N] = E;
}

// --- Partitioned CSR column fill (u16) ---
__global__ __launch_bounds__(256) void build_col_part(const int* __restrict__ src,
                                                      const int* __restrict__ dst,
                                                      int* __restrict__ cursor,
                                                      unsigned short* __restrict__ col,
                                                      int E, int N) {
    int g    = blockIdx.x & (NXCD - 1);
    int bpg  = blockIdx.x >> 3;
    int nbpg = gridDim.x >> 3;
    int chunk = (N + NXCD - 1) / NXCD;
    int lo = g * chunk;
    int hi = min(N, lo + chunk);
    for (int e = bpg * 256 + threadIdx.x; e < E; e += nbpg * 256) {
        int s = src[e];
        if (s >= lo && s < hi) {
            int pos = atomicAdd(&cursor[s], 1);
            col[pos] = (unsigned short)dst[e];
        }
    }
}

// One wave per node. Lane (half,sub): half 0 handles even-slot edges, half 1
// odd-slot; each lane loads half2 (dims 2*sub, 2*sub+1). 16 edges in flight.
__global__ __launch_bounds__(256) void gather_mean_h2(const __half* __restrict__ H,
                                                      const int* __restrict__ rowptr,
                                                      const unsigned short* __restrict__ col,
                                                      float* __restrict__ out, int N) {
    int node = blockIdx.x * 4 + (threadIdx.x >> 6);
    int lane = threadIdx.x & 63;
    if (node >= N) return;
    const int half = lane >> 5;
    const int sub  = lane & 31;
    const int beg = rowptr[node];
    const int end = rowptr[node + 1];
    const int deg = end - beg;
    const __half2* __restrict__ H2 = (const __half2*)H;
    float ax = 0.f, ay = 0.f;
    int e = beg;
    for (; e + 16 <= end; e += 16) {            // 8 paired iterations = 16 edges in flight
        int t0 = col[e +  0 + half], t1 = col[e +  2 + half];
        int t2 = col[e +  4 + half], t3 = col[e +  6 + half];
        int t4 = col[e +  8 + half], t5 = col[e + 10 + half];
        int t6 = col[e + 12 + half], t7 = col[e + 14 + half];
        float2 f0 = __half22float2(H2[(size_t)t0 * 32 + sub]);
        float2 f1 = __half22float2(H2[(size_t)t1 * 32 + sub]);
        float2 f2 = __half22float2(H2[(size_t)t2 * 32 + sub]);
        float2 f3 = __half22float2(H2[(size_t)t3 * 32 + sub]);
        float2 f4 = __half22float2(H2[(size_t)t4 * 32 + sub]);
        float2 f5 = __half22float2(H2[(size_t)t5 * 32 + sub]);
        float2 f6 = __half22float2(H2[(size_t)t6 * 32 + sub]);
        float2 f7 = __half22float2(H2[(size_t)t7 * 32 + sub]);
        ax += ((f0.x + f1.x) + (f2.x + f3.x)) + ((f4.x + f5.x) + (f6.x + f7.x));
        ay += ((f0.y + f1.y) + (f2.y + f3.y)) + ((f4.y + f5.y) + (f6.y + f7.y));
    }
    for (; e + 2 <= end; e += 2) {
        int t = col[e + half];
        float2 f = __half22float2(H2[(size_t)t * 32 + sub]);
        ax += f.x; ay += f.y;
    }
    if (e < end && half == 0) {                 // odd-degree tail: low half only
        float2 f = __half22float2(H2[(size_t)col[e] * 32 + sub]);
        ax += f.x; ay += f.y;
    }
    ax += __shfl_xor(ax, 32);
    ay += __shfl_xor(ay, 32);
    if (half == 0) {
        float inv = (deg > 0) ? 1.f / (float)deg : 0.f;
        float2 o; o.x = ax * inv; o.y = ay * inv;
        ((float2*)out)[(size_t)node * 32 + sub] = o;
    }
}

// Chunked 16-FMA body: acc += xrow[0..15] . wreg[0..15]
__device__ __forceinline__ float dot16(const float* xrow, const float* wreg, float a) {
    float4 x0 = *(const float4*)(xrow + 0);
    float4 x1 = *(const float4*)(xrow + 4);
    float4 x2 = *(const float4*)(xrow + 8);
    float4 x3 = *(const float4*)(xrow + 12);
    a = fmaf(x0.x, wreg[0], a);  a = fmaf(x0.y, wreg[1], a);
    a = fmaf(x0.z, wreg[2], a);  a = fmaf(x0.w, wreg[3], a);
    a = fmaf(x1.x, wreg[4], a);  a = fmaf(x1.y, wreg[5], a);
    a = fmaf(x1.z, wreg[6], a);  a = fmaf(x1.w, wreg[7], a);
    a = fmaf(x2.x, wreg[8], a);  a = fmaf(x2.y, wreg[9], a);
    a = fmaf(x2.z, wreg[10], a); a = fmaf(x2.w, wreg[11], a);
    a = fmaf(x3.x, wreg[12], a); a = fmaf(x3.y, wreg[13], a);
    a = fmaf(x3.z, wreg[14], a); a = fmaf(x3.w, wreg[15], a);
    return a;
}

// Y[n x 64] = (optional relu)(X[n x 64]) @ W + b. 16 rows/block (4 rows/wave).
template <bool RELU_IN, bool HALF_OUT>
__global__ __launch_bounds__(256) void gemm64(const float* __restrict__ X,
                                              const float* __restrict__ W,
                                              const float* __restrict__ b,
                                              void* __restrict__ Yv, int n) {
    __shared__ float xs[16][64];
    const int tid  = threadIdx.x;
    const int lane = tid & 63;
    const int wid  = tid >> 6;
    const int row0 = blockIdx.x * 16;

    for (int i = tid; i < 16 * 64; i += 256) {
        int rr = row0 + (i >> 6);
        float v = (rr < n) ? X[(size_t)row0 * 64 + i] : 0.f;
        if (RELU_IN) v = fmaxf(v, 0.f);
        xs[i >> 6][i & 63] = v;
    }
    const float bias = b[lane];
    __syncthreads();

    float acc[4];
#pragma unroll
    for (int r = 0; r < 4; ++r) acc[r] = bias;
#pragma unroll 1
    for (int c = 0; c < 4; ++c) {
        float wreg[16];
#pragma unroll
        for (int j = 0; j < 16; ++j) wreg[j] = W[(c * 16 + j) * 64 + lane];
#pragma unroll
        for (int r = 0; r < 4; ++r)
            acc[r] = dot16(&xs[wid * 4 + r][c * 16], wreg, acc[r]);
    }

#pragma unroll
    for (int r = 0; r < 4; ++r) {
        const int grow = row0 + wid * 4 + r;
        if (grow < n) {
            if (HALF_OUT) ((__half*)Yv)[(size_t)grow * 64 + lane] = __float2half(acc[r]);
            else          ((float*)Yv)[(size_t)grow * 64 + lane] = acc[r];
        }
    }
}

// out[row] = log_softmax( (relu(A2[row]) @ Wp1 + bp1) @ Wp2 + bp2 ). 16 rows/block.
__global__ __launch_bounds__(256) void fused_post(const float* __restrict__ A2,
                                                  const float* __restrict__ Wp1,
                                                  const float* __restrict__ bp1,
                                                  const float* __restrict__ Wp2,
                                                  const float* __restrict__ bp2,
                                                  float* __restrict__ out, int n) {
    __shared__ float xs[16][64];
    __shared__ float ys[16][64];
    const int tid  = threadIdx.x;
    const int lane = tid & 63;
    const int wid  = tid >> 6;
    const int row0 = blockIdx.x * 16;

    for (int i = tid; i < 16 * 64; i += 256) {
        int rr = row0 + (i >> 6);
        float v = (rr < n) ? A2[(size_t)row0 * 64 + i] : 0.f;
        xs[i >> 6][i & 63] = fmaxf(v, 0.f);
    }
    const float bias1 = bp1[lane];
    __syncthreads();

    // GEMM1 -> ys (wave-private rows; no second barrier needed).
    float acc[4];
#pragma unroll
    for (int r = 0; r < 4; ++r) acc[r] = bias1;
#pragma unroll 1
    for (int c = 0; c < 4; ++c) {
        float wreg[16];
#pragma unroll
        for (int j = 0; j < 16; ++j) wreg[j] = Wp1[(c * 16 + j) * 64 + lane];
#pragma unroll
        for (int r = 0; r < 4; ++r)
            acc[r] = dot16(&xs[wid * 4 + r][c * 16], wreg, acc[r]);
    }
#pragma unroll
    for (int r = 0; r < 4; ++r) ys[wid * 4 + r][lane] = acc[r];

    // GEMM2 (KOUT=40) + log_softmax.
    const float bias2 = (lane < 40) ? bp2[lane] : 0.f;
#pragma unroll
    for (int r = 0; r < 4; ++r) acc[r] = bias2;
#pragma unroll 1
    for (int c = 0; c < 4; ++c) {
        float wreg[16];
#pragma unroll
        for (int j = 0; j < 16; ++j)
            wreg[j] = (lane < 40) ? Wp2[(c * 16 + j) * 40 + lane] : 0.f;
#pragma unroll
        for (int r = 0; r < 4; ++r)
            acc[r] = dot16(&ys[wid * 4 + r][c * 16], wreg, acc[r]);
    }

#pragma unroll
    for (int r = 0; r < 4; ++r) {
        float vm = (lane < 40) ? acc[r] : -INFINITY;
        float m = vm;
#pragma unroll
        for (int o = 32; o; o >>= 1) m = fmaxf(m, __shfl_xor(m, o));
        float e = (lane < 40) ? expf(vm - m) : 0.f;
        float s = e;
#pragma unroll
        for (int o = 32; o; o >>= 1) s += __shfl_xor(s, o);
        float ls = logf(s);
        const int grow = row0 + wid * 4 + r;
        if (grow < n && lane < 40) out[(size_t)grow * 40 + lane] = vm - m - ls;
    }
}

extern "C" void kernel_launch(void* const* d_in, const int* in_sizes, int n_in,
                              void* d_out, int out_size, void* d_ws, size_t ws_size,
                              hipStream_t stream) {
    const float* x   = (const float*)d_in[0];
    const int*   ei  = (const int*)d_in[1];
    const float* W1  = (const float*)d_in[2];
    const float* b1  = (const float*)d_in[3];
    const float* W2  = (const float*)d_in[4];
    const float* b2  = (const float*)d_in[5];
    const float* Wp1 = (const float*)d_in[6];
    const float* bp1 = (const float*)d_in[7];
    const float* Wp2 = (const float*)d_in[8];
    const float* bp2 = (const float*)d_in[9];
    float* out = (float*)d_out;

    const int N = in_sizes[0] / 64;
    const int E = in_sizes[1] / 2;
    const int* src = ei;
    const int* dst = ei + E;

    // Workspace layout
    char*  wsb = (char*)d_ws;
    size_t off = 0;
    auto alloc = [&](size_t bytes) { void* p = wsb + off; off += (bytes + 511) & ~(size_t)511; return p; };
    int*            deg       = (int*)alloc((size_t)N * 4);
    int*            rowptr    = (int*)alloc((size_t)(N + 1) * 4);
    int*            cursor    = (int*)alloc((size_t)N * 4);
    int*            chunkScan = (int*)alloc((size_t)N * 4);
    int*            blockSums = (int*)alloc((size_t)SCAN_BS * 4);
    unsigned short* col       = (unsigned short*)alloc((size_t)E * 2);
    __half*         Hh        = (__half*)alloc((size_t)N * 64 * 2);   // H1 / H2 (fp16)
    float*          A         = (float*)alloc((size_t)N * 64 * 4);    // A1 / A2 (fp32)
    (void)ws_size; (void)n_in; (void)out_size;

    const int scanBlocks = (N + SCAN_BS - 1) / SCAN_BS;
    const int nb16       = (N + 15) / 16;
    const int nodeBlocks = (N + 3) / 4;
    const int partBlocks = 1024;

    // --- Build CSR ---
    hipMemsetAsync(deg, 0, (size_t)N * 4, stream);
    count_deg_part<<<partBlocks, 256, 0, stream>>>(src, deg, E, N);
    scan1_kernel<<<scanBlocks, SCAN_BS, 0, stream>>>(deg, chunkScan, blockSums, N);
    scan2_kernel<<<1, SCAN_BS, 0, stream>>>(blockSums, scanBlocks);
    scan3_kernel<<<(N + 255) / 256, 256, 0, stream>>>(chunkScan, blockSums, rowptr, cursor, N, E);
    build_col_part<<<partBlocks, 256, 0, stream>>>(src, dst, cursor, col, E, N);

    // --- Pipeline ---
    gemm64<false, true><<<nb16, 256, 0, stream>>>(x, W1, b1, Hh, N);              // H1 (fp16)
    gather_mean_h2<<<nodeBlocks, 256, 0, stream>>>(Hh, rowptr, col, A, N);        // A1 (fp32)
    gemm64<true, true><<<nb16, 256, 0, stream>>>(A, W2, b2, Hh, N);               // H2 (fp16, relu in)
    gather_mean_h2<<<nodeBlocks, 256, 0, stream>>>(Hh, rowptr, col, A, N);        // A2 (fp32)
    fused_post<<<nb16, 256, 0, stream>>>(A, Wp1, bp1, Wp2, bp2, out, N);          // out
}

// Round 8
// 232.081 us; speedup vs baseline: 1.0036x; 1.0036x over previous
//
#include <hip/hip_runtime.h>
#include <cmath>

// GraphSAGE forward for MI355X (gfx950).
// R8: fp16 everywhere (hidden states, transposed weights), dense math via
//     v_dot2_f32_f16 (fdot2): halves VALU ops, LDS traffic, W-load bytes.
//     Relu fused into gather epilogue. CSR build unchanged.

typedef _Float16 half_t;
typedef half_t half2_t __attribute__((ext_vector_type(2)));

#if defined(__has_builtin)
# if __has_builtin(__builtin_amdgcn_fdot2)
#  define FDOT2(a, b, c) __builtin_amdgcn_fdot2((a), (b), (c), false)
# endif
#endif
#ifndef FDOT2
# define FDOT2(a, b, c) fmaf((float)(a)[0], (float)(b)[0], fmaf((float)(a)[1], (float)(b)[1], (c)))
#endif

#define SCAN_BS 512
#define NXCD 8

// --- Partitioned degree count ---
__global__ __launch_bounds__(256) void count_deg_part(const int* __restrict__ src,
                                                      int* __restrict__ deg, int E, int N) {
    int g    = blockIdx.x & (NXCD - 1);
    int bpg  = blockIdx.x >> 3;
    int nbpg = gridDim.x >> 3;
    int chunk = (N + NXCD - 1) / NXCD;
    int lo = g * chunk;
    int hi = min(N, lo + chunk);
    for (int e = bpg * 256 + threadIdx.x; e < E; e += nbpg * 256) {
        int s = src[e];
        if (s >= lo && s < hi) atomicAdd(&deg[s], 1);
    }
}

// --- 3-phase exclusive scan of deg[N] -> rowptr[N+1] (+ cursor copy) ---
__global__ __launch_bounds__(SCAN_BS) void scan1_kernel(const int* __restrict__ deg,
                                                        int* __restrict__ chunkScan,
                                                        int* __restrict__ blockSums, int N) {
    __shared__ int tmp[SCAN_BS];
    int gid = blockIdx.x * SCAN_BS + threadIdx.x;
    int v = (gid < N) ? deg[gid] : 0;
    tmp[threadIdx.x] = v;
    __syncthreads();
    for (int off = 1; off < SCAN_BS; off <<= 1) {
        int add = (threadIdx.x >= off) ? tmp[threadIdx.x - off] : 0;
        __syncthreads();
        tmp[threadIdx.x] += add;
        __syncthreads();
    }
    if (gid < N) chunkScan[gid] = tmp[threadIdx.x] - v;
    if (threadIdx.x == SCAN_BS - 1) blockSums[blockIdx.x] = tmp[threadIdx.x];
}

__global__ __launch_bounds__(SCAN_BS) void scan2_kernel(int* __restrict__ blockSums, int nb) {
    __shared__ int tmp[SCAN_BS];
    int v = (threadIdx.x < nb) ? blockSums[threadIdx.x] : 0;
    tmp[threadIdx.x] = v;
    __syncthreads();
    for (int off = 1; off < SCAN_BS; off <<= 1) {
        int add = (threadIdx.x >= off) ? tmp[threadIdx.x - off] : 0;
        __syncthreads();
        tmp[threadIdx.x] += add;
        __syncthreads();
    }
    if (threadIdx.x < nb) blockSums[threadIdx.x] = tmp[threadIdx.x] - v;
}

__global__ void scan3_kernel(const int* __restrict__ chunkScan, const int* __restrict__ blockSums,
                             int* __restrict__ rowptr, int* __restrict__ cursor, int N, int E) {
    int gid = blockIdx.x * blockDim.x + threadIdx.x;
    if (gid < N) {
        int v = chunkScan[gid] + blockSums[gid / SCAN_BS];
        rowptr[gid] = v;
        cursor[gid] = v;
    }
    if (gid == 0) rowptr[N] = E;
}

// --- Partitioned CSR column fill (u16) ---
__global__ __launch_bounds__(256) void build_col_part(const int* __restrict__ src,
                                                      const int* __restrict__ dst,
                                                      int* __restrict__ cursor,
                                                      unsigned short* __restrict__ col,
                                                      int E, int N) {
    int g    = blockIdx.x & (NXCD - 1);
    int bpg  = blockIdx.x >> 3;
    int nbpg = gridDim.x >> 3;
    int chunk = (N + NXCD - 1) / NXCD;
    int lo = g * chunk;
    int hi = min(N, lo + chunk);
    for (int e = bpg * 256 + threadIdx.x; e < E; e += nbpg * 256) {
        int s = src[e];
        if (s >= lo && s < hi) {
            int pos = atomicAdd(&cursor[s], 1);
            col[pos] = (unsigned short)dst[e];
        }
    }
}

// Weight convert+transpose: T = concat(W1^T, W2^T, Wp1^T, Wp2^T padded) as fp16.
// T[w][c*64+k]; Wp2 pad cols 40..63 with 0.
__global__ void wconv_kernel(const float* __restrict__ W1, const float* __restrict__ W2,
                             const float* __restrict__ Wp1, const float* __restrict__ Wp2,
                             half_t* __restrict__ T) {
    int i = blockIdx.x * blockDim.x + threadIdx.x;
    if (i >= 4 * 4096) return;
    int which = i >> 12, r = i & 4095;
    int c = r >> 6, k = r & 63;
    float v;
    if      (which == 0) v = W1[k * 64 + c];
    else if (which == 1) v = W2[k * 64 + c];
    else if (which == 2) v = Wp1[k * 64 + c];
    else                 v = (c < 40) ? Wp2[k * 40 + c] : 0.f;
    T[i] = (half_t)v;
}

// One wave per node; split-wave half2 gather (16 edges in flight), fp32 accum,
// fused relu, fp16 output.
__global__ __launch_bounds__(256) void gather_mean_relu(const half_t* __restrict__ H,
                                                        const int* __restrict__ rowptr,
                                                        const unsigned short* __restrict__ col,
                                                        half_t* __restrict__ outh, int N) {
    int node = blockIdx.x * 4 + (threadIdx.x >> 6);
    int lane = threadIdx.x & 63;
    if (node >= N) return;
    const int hf  = lane >> 5;
    const int sub = lane & 31;
    const int beg = rowptr[node];
    const int end = rowptr[node + 1];
    const int deg = end - beg;
    const half2_t* __restrict__ H2 = (const half2_t*)H;
    float ax = 0.f, ay = 0.f;
    int e = beg;
    for (; e + 16 <= end; e += 16) {
        int t0 = col[e +  0 + hf], t1 = col[e +  2 + hf];
        int t2 = col[e +  4 + hf], t3 = col[e +  6 + hf];
        int t4 = col[e +  8 + hf], t5 = col[e + 10 + hf];
        int t6 = col[e + 12 + hf], t7 = col[e + 14 + hf];
        half2_t f0 = H2[(size_t)t0 * 32 + sub];
        half2_t f1 = H2[(size_t)t1 * 32 + sub];
        half2_t f2 = H2[(size_t)t2 * 32 + sub];
        half2_t f3 = H2[(size_t)t3 * 32 + sub];
        half2_t f4 = H2[(size_t)t4 * 32 + sub];
        half2_t f5 = H2[(size_t)t5 * 32 + sub];
        half2_t f6 = H2[(size_t)t6 * 32 + sub];
        half2_t f7 = H2[(size_t)t7 * 32 + sub];
        ax += (((float)f0[0] + (float)f1[0]) + ((float)f2[0] + (float)f3[0]))
            + (((float)f4[0] + (float)f5[0]) + ((float)f6[0] + (float)f7[0]));
        ay += (((float)f0[1] + (float)f1[1]) + ((float)f2[1] + (float)f3[1]))
            + (((float)f4[1] + (float)f5[1]) + ((float)f6[1] + (float)f7[1]));
    }
    for (; e + 2 <= end; e += 2) {
        half2_t f = H2[(size_t)col[e + hf] * 32 + sub];
        ax += (float)f[0]; ay += (float)f[1];
    }
    if (e < end && hf == 0) {
        half2_t f = H2[(size_t)col[e] * 32 + sub];
        ax += (float)f[0]; ay += (float)f[1];
    }
    ax += __shfl_xor(ax, 32);
    ay += __shfl_xor(ay, 32);
    if (hf == 0) {
        float inv = (deg > 0) ? 1.f / (float)deg : 0.f;
        half2_t o;
        o[0] = (half_t)fmaxf(ax * inv, 0.f);
        o[1] = (half_t)fmaxf(ay * inv, 0.f);
        ((half2_t*)outh)[(size_t)node * 32 + sub] = o;
    }
}

// Y[n x 64] (fp16) = X @ W + b via fdot2. Wt is transposed fp16 [c][k].
// CONV_IN: X is fp32 (convert during staging), else fp16.
template <bool CONV_IN>
__global__ __launch_bounds__(256) void gemm64h(const void* __restrict__ Xv,
                                               const half_t* __restrict__ Wt,
                                               const float* __restrict__ b,
                                               half_t* __restrict__ Y, int n) {
    __shared__ half_t xs[16][64];
    const int tid  = threadIdx.x;
    const int lane = tid & 63;
    const int wid  = tid >> 6;
    const int row0 = blockIdx.x * 16;

    if (CONV_IN) {
        const float* X = (const float*)Xv;
        for (int i = tid; i < 16 * 64; i += 256) {
            int rr = row0 + (i >> 6);
            float v = (rr < n) ? X[(size_t)row0 * 64 + i] : 0.f;
            xs[i >> 6][i & 63] = (half_t)v;
        }
    } else {
        const half2_t* X2 = (const half2_t*)Xv;
        half2_t z; z[0] = (half_t)0.f; z[1] = (half_t)0.f;
        for (int i = tid; i < 16 * 32; i += 256) {
            int rr = row0 + (i >> 5);
            ((half2_t*)xs)[i] = (rr < n) ? X2[(size_t)row0 * 32 + i] : z;
        }
    }
    const float bias = b[lane];
    __syncthreads();

    float acc[4] = {bias, bias, bias, bias};
    const half2_t* wcol = (const half2_t*)(Wt + (size_t)lane * 64);
#pragma unroll
    for (int c = 0; c < 4; ++c) {
        half2_t wr[8];
#pragma unroll
        for (int i = 0; i < 8; ++i) wr[i] = wcol[c * 8 + i];
#pragma unroll
        for (int r = 0; r < 4; ++r) {
            const half2_t* xp = (const half2_t*)&xs[wid * 4 + r][c * 16];
#pragma unroll
            for (int i = 0; i < 8; ++i) acc[r] = FDOT2(xp[i], wr[i], acc[r]);
        }
    }
#pragma unroll
    for (int r = 0; r < 4; ++r) {
        int grow = row0 + wid * 4 + r;
        if (grow < n) Y[(size_t)grow * 64 + lane] = (half_t)acc[r];
    }
}

// out[row] = log_softmax( (A2h[row] @ Wp1 + bp1) @ Wp2 + bp2 )  [A2h pre-relu'd fp16]
__global__ __launch_bounds__(256) void fused_post_h(const half_t* __restrict__ Ah,
                                                    const half_t* __restrict__ Wt1,
                                                    const float* __restrict__ bp1,
                                                    const half_t* __restrict__ Wt2,
                                                    const float* __restrict__ bp2,
                                                    float* __restrict__ out, int n) {
    __shared__ half_t xs[16][64];
    __shared__ half_t ys[16][64];
    const int tid  = threadIdx.x;
    const int lane = tid & 63;
    const int wid  = tid >> 6;
    const int row0 = blockIdx.x * 16;

    {
        const half2_t* X2 = (const half2_t*)Ah;
        half2_t z; z[0] = (half_t)0.f; z[1] = (half_t)0.f;
        for (int i = tid; i < 16 * 32; i += 256) {
            int rr = row0 + (i >> 5);
            ((half2_t*)xs)[i] = (rr < n) ? X2[(size_t)row0 * 32 + i] : z;
        }
    }
    const float bias1 = bp1[lane];
    __syncthreads();

    // GEMM1 -> ys (wave-private rows; no barrier needed before reuse).
    float acc[4] = {bias1, bias1, bias1, bias1};
    const half2_t* wcol1 = (const half2_t*)(Wt1 + (size_t)lane * 64);
#pragma unroll
    for (int c = 0; c < 4; ++c) {
        half2_t wr[8];
#pragma unroll
        for (int i = 0; i < 8; ++i) wr[i] = wcol1[c * 8 + i];
#pragma unroll
        for (int r = 0; r < 4; ++r) {
            const half2_t* xp = (const half2_t*)&xs[wid * 4 + r][c * 16];
#pragma unroll
            for (int i = 0; i < 8; ++i) acc[r] = FDOT2(xp[i], wr[i], acc[r]);
        }
    }
#pragma unroll
    for (int r = 0; r < 4; ++r) ys[wid * 4 + r][lane] = (half_t)acc[r];

    // GEMM2 (Wp2^T padded to 64 cols; lanes >= 40 compute garbage, masked below).
    const float bias2 = (lane < 40) ? bp2[lane] : 0.f;
#pragma unroll
    for (int r = 0; r < 4; ++r) acc[r] = bias2;
    const half2_t* wcol2 = (const half2_t*)(Wt2 + (size_t)lane * 64);
#pragma unroll
    for (int c = 0; c < 4; ++c) {
        half2_t wr[8];
#pragma unroll
        for (int i = 0; i < 8; ++i) wr[i] = wcol2[c * 8 + i];
#pragma unroll
        for (int r = 0; r < 4; ++r) {
            const half2_t* xp = (const half2_t*)&ys[wid * 4 + r][c * 16];
#pragma unroll
            for (int i = 0; i < 8; ++i) acc[r] = FDOT2(xp[i], wr[i], acc[r]);
        }
    }

#pragma unroll
    for (int r = 0; r < 4; ++r) {
        float vm = (lane < 40) ? acc[r] : -INFINITY;
        float m = vm;
#pragma unroll
        for (int o = 32; o; o >>= 1) m = fmaxf(m, __shfl_xor(m, o));
        float e = (lane < 40) ? expf(vm - m) : 0.f;
        float s = e;
#pragma unroll
        for (int o = 32; o; o >>= 1) s += __shfl_xor(s, o);
        float ls = logf(s);
        const int grow = row0 + wid * 4 + r;
        if (grow < n && lane < 40) out[(size_t)grow * 40 + lane] = vm - m - ls;
    }
}

extern "C" void kernel_launch(void* const* d_in, const int* in_sizes, int n_in,
                              void* d_out, int out_size, void* d_ws, size_t ws_size,
                              hipStream_t stream) {
    const float* x   = (const float*)d_in[0];
    const int*   ei  = (const int*)d_in[1];
    const float* W1  = (const float*)d_in[2];
    const float* b1  = (const float*)d_in[3];
    const float* W2  = (const float*)d_in[4];
    const float* b2  = (const float*)d_in[5];
    const float* Wp1 = (const float*)d_in[6];
    const float* bp1 = (const float*)d_in[7];
    const float* Wp2 = (const float*)d_in[8];
    const float* bp2 = (const float*)d_in[9];
    float* out = (float*)d_out;

    const int N = in_sizes[0] / 64;
    const int E = in_sizes[1] / 2;
    const int* src = ei;
    const int* dst = ei + E;

    // Workspace layout
    char*  wsb = (char*)d_ws;
    size_t off = 0;
    auto alloc = [&](size_t bytes) { void* p = wsb + off; off += (bytes + 511) & ~(size_t)511; return p; };
    int*            deg       = (int*)alloc((size_t)N * 4);
    int*            rowptr    = (int*)alloc((size_t)(N + 1) * 4);
    int*            cursor    = (int*)alloc((size_t)N * 4);
    int*            chunkScan = (int*)alloc((size_t)N * 4);
    int*            blockSums = (int*)alloc((size_t)SCAN_BS * 4);
    unsigned short* col       = (unsigned short*)alloc((size_t)E * 2);
    half_t*         Wt        = (half_t*)alloc((size_t)4 * 4096 * 2);  // W1^T,W2^T,Wp1^T,Wp2^T(pad)
    half_t*         Hh        = (half_t*)alloc((size_t)N * 64 * 2);    // H1 / H2
    half_t*         Ah        = (half_t*)alloc((size_t)N * 64 * 2);    // relu'd A1 / A2
    (void)ws_size; (void)n_in; (void)out_size;

    const int scanBlocks = (N + SCAN_BS - 1) / SCAN_BS;
    const int nb16       = (N + 15) / 16;
    const int nodeBlocks = (N + 3) / 4;
    const int partBlocks = 1024;

    // --- Build CSR + weight convert ---
    hipMemsetAsync(deg, 0, (size_t)N * 4, stream);
    wconv_kernel<<<64, 256, 0, stream>>>(W1, W2, Wp1, Wp2, Wt);
    count_deg_part<<<partBlocks, 256, 0, stream>>>(src, deg, E, N);
    scan1_kernel<<<scanBlocks, SCAN_BS, 0, stream>>>(deg, chunkScan, blockSums, N);
    scan2_kernel<<<1, SCAN_BS, 0, stream>>>(blockSums, scanBlocks);
    scan3_kernel<<<(N + 255) / 256, 256, 0, stream>>>(chunkScan, blockSums, rowptr, cursor, N, E);
    build_col_part<<<partBlocks, 256, 0, stream>>>(src, dst, cursor, col, E, N);

    // --- Pipeline (all hidden states fp16) ---
    gemm64h<true ><<<nb16, 256, 0, stream>>>(x,  Wt + 0 * 4096, b1, Hh, N);        // H1
    gather_mean_relu<<<nodeBlocks, 256, 0, stream>>>(Hh, rowptr, col, Ah, N);      // relu(A1)
    gemm64h<false><<<nb16, 256, 0, stream>>>(Ah, Wt + 1 * 4096, b2, Hh, N);        // H2
    gather_mean_relu<<<nodeBlocks, 256, 0, stream>>>(Hh, rowptr, col, Ah, N);      // relu(A2)
    fused_post_h<<<nb16, 256, 0, stream>>>(Ah, Wt + 2 * 4096, bp1,
                                           Wt + 3 * 4096, bp2, out, N);            // out
}